// Round 7
// baseline (274.937 us; speedup 1.0000x reference)
//
#include <hip/hip_runtime.h>
#include <hip/hip_bf16.h>
#include <stdint.h>

typedef __attribute__((ext_vector_type(8))) short short8;
typedef __attribute__((ext_vector_type(4))) float f32x4;

#define M_DIM 8192
#define N_DIM 4096
#define K_DIM 4096
#define BM 256
#define BN 256
#define BK 64

static __device__ __forceinline__ unsigned short f32_to_bf16(float f) {
  union { float f; unsigned int u; } v; v.f = f;
  unsigned int u = v.u;
  u += 0x7fffu + ((u >> 16) & 1u);   // round-to-nearest-even
  return (unsigned short)(u >> 16);
}

// ---------------- cast x (f32 -> bf16), 8 elems/thread ----------------
__global__ void cast_x_kernel(const float* __restrict__ x,
                              unsigned short* __restrict__ xb) {
  size_t i = ((size_t)blockIdx.x * blockDim.x + threadIdx.x) * 8;
  if (i >= (size_t)M_DIM * K_DIM) return;
  float4 v0 = *reinterpret_cast<const float4*>(x + i);
  float4 v1 = *reinterpret_cast<const float4*>(x + i + 4);
  short8 o;
  o[0] = (short)f32_to_bf16(v0.x);
  o[1] = (short)f32_to_bf16(v0.y);
  o[2] = (short)f32_to_bf16(v0.z);
  o[3] = (short)f32_to_bf16(v0.w);
  o[4] = (short)f32_to_bf16(v1.x);
  o[5] = (short)f32_to_bf16(v1.y);
  o[6] = (short)f32_to_bf16(v1.z);
  o[7] = (short)f32_to_bf16(v1.w);
  *reinterpret_cast<short8*>(xb + i) = o;
}

// ---------------- dequant: bit-planes -> bf16 W[N][K] (validated) ----------
__global__ void dequant_kernel(const int* __restrict__ qw,
                               const float* __restrict__ scale,
                               const float* __restrict__ zero,
                               unsigned short* __restrict__ W) {
  int idx = blockIdx.x * blockDim.x + threadIdx.x;   // n*128 + c
  if (idx >= N_DIM * 128) return;
  int n = idx >> 7;
  int c = idx & 127;
  unsigned int w[8];
#pragma unroll
  for (int k = 0; k < 8; ++k)
    w[k] = (unsigned int)qw[(size_t)k * (N_DIM * 128) + idx];
  int wp = c >> 5, t = c & 31;
#pragma unroll
  for (int s = 0; s < 4; ++s) {
    int r = s ^ 3;
    unsigned int by[8];
#pragma unroll
    for (int k = 0; k < 8; ++k) by[k] = (w[k] >> (8 * r)) & 0xffu;
    int ibase = wp * 1024 + s * 256 + t * 8;
    int g = ibase >> 7;
    float sc = scale[n * 32 + g];
    float zp = zero[n * 32 + g] * 16.0f;
    short8 o;
#pragma unroll
    for (int u = 0; u < 8; ++u) {
      unsigned int q = 0;
#pragma unroll
      for (int k = 0; k < 8; ++k)
        q |= ((by[k] >> (7 - u)) & 1u) << (7 - k);
      o[u] = (short)f32_to_bf16(sc * ((float)q - zp));
    }
    *reinterpret_cast<short8*>(&W[(size_t)n * K_DIM + ibase]) = o;
  }
}

// ---- 256x256 8-region bf16 GEMM, register-ping-pong operand pipeline ----
// C[M][N] = A[M][K] * B[N][K]^T + bias. 8 waves (2Mx4N), wave out 128x64.
// Operand sets a0_/a1_ (A q0/q1), b0_/b1_ (B q0/q1) double-buffer across the
// Gray walk (0,0)(0,1)(1,1)(1,0). Loads for region p+1 issue at p's START
// (pinned before MFMA via SB0) -> full MFMA shadow; next lgkm(0) ~free.
// B-q0 dedup: 48 b128/iter (was 56) -> LDS port 576 cyc < MFMA 621 floor.
// VISIBILITY (corrected): vmcnt drain at region d (after d's barrier) makes
// data readable from d+1 (next barrier). Steady state: pair staged at s is
// drained at s+2 entry -> readable s+3. All read edges verified; overwrite
// edges all >= last-read+2 (lgkm at r+1 entry bounds cross-wave reads).

#define VMCNT2 asm volatile("s_waitcnt vmcnt(2)" ::: "memory")
#define VMCNT0 asm volatile("s_waitcnt vmcnt(0)" ::: "memory")
#define NOOP ((void)0)

#define STG(G, GROWB, KT, LDSC) do {                                           \
  const unsigned short* sb_ = (G) + ((size_t)(GROWB) * K_DIM + (KT) * 64);     \
  __builtin_amdgcn_global_load_lds(                                            \
      (const __attribute__((address_space(1))) void*)(sb_ + s_off0),           \
      (__attribute__((address_space(3))) void*)(smem + (LDSC) + wslot),        \
      16, 0, 0);                                                               \
  __builtin_amdgcn_global_load_lds(                                            \
      (const __attribute__((address_space(1))) void*)(sb_ + s_off1),           \
      (__attribute__((address_space(3))) void*)(smem + (LDSC) + 8192 + wslot), \
      16, 0, 0);                                                               \
} while (0)
#define STG_A(BUF, H, KT) STG(Ag, m0 + (H)*128, (KT), ((BUF)*2 + (H)) * 16384)
#define STG_B(BUF, H, KT) STG(Bg, n0 + (H)*128, (KT), 65536 + ((BUF)*2 + (H)) * 16384)

// one k-slot (KK literal) of an A set: 4 x ds_read_b128
#define LA_K(SET, BUF, QM, KK) do {                                            \
  _Pragma("unroll") for (int mf_ = 0; mf_ < 4; ++mf_)                          \
    SET[mf_][KK] = *(const short8*)(smem + ((KK) ? a_off1 : a_off0) +          \
        (((BUF)*2 + (QM)) * 16384 + mf_ * 2048));                              \
} while (0)
#define LA_ALL(SET, BUF, QM) do { LA_K(SET, BUF, QM, 0); LA_K(SET, BUF, QM, 1); } while (0)
// full B set (both kk): 4 x ds_read_b128
#define LB_ALL(SET, BUF, QN) do {                                              \
  _Pragma("unroll") for (int nf_ = 0; nf_ < 2; ++nf_) {                        \
    SET[nf_][0] = *(const short8*)(smem + b_off0 +                             \
        (((BUF)*2 + (QN)) * 16384 + nf_ * 2048));                              \
    SET[nf_][1] = *(const short8*)(smem + b_off1 +                             \
        (((BUF)*2 + (QN)) * 16384 + nf_ * 2048));                              \
  } } while (0)

// region: bar; WAITV; lgkm0; SB0; prio1; {stage; early-rds} SB0 MFMA16; late; prio0
#define REGION(QM, QN, AS, BS, EARLY, STAGE, LATE, WAITV) do {                 \
  __builtin_amdgcn_s_barrier();                                                \
  WAITV;                                                                       \
  asm volatile("s_waitcnt lgkmcnt(0)" ::: "memory");                           \
  __builtin_amdgcn_sched_barrier(0);                                           \
  __builtin_amdgcn_s_setprio(1);                                               \
  STAGE;                                                                       \
  EARLY;                                                                       \
  __builtin_amdgcn_sched_barrier(0);                                           \
  _Pragma("unroll") for (int mf_ = 0; mf_ < 4; ++mf_)                          \
    _Pragma("unroll") for (int nf_ = 0; nf_ < 2; ++nf_)                        \
      _Pragma("unroll") for (int kk_ = 0; kk_ < 2; ++kk_)                      \
        acc[QM][QN][mf_][nf_] = __builtin_amdgcn_mfma_f32_16x16x32_bf16(       \
            AS[mf_][kk_], BS[nf_][kk_], acc[QM][QN][mf_][nf_], 0, 0, 0);       \
  LATE;                                                                        \
  __builtin_amdgcn_s_setprio(0);                                               \
} while (0)

__global__ __launch_bounds__(512, 2) void gemm_kernel(
    const unsigned short* __restrict__ Ag,   // Xb [M][K] bf16
    const unsigned short* __restrict__ Bg,   // Wb [N][K] bf16
    const float* __restrict__ bias,
    float* __restrict__ C) {
  __shared__ __align__(16) char smem[131072];   // A: [0,64K), B: [64K,128K)

  // XCD-aware bijective swizzle: 512 blocks % 8 == 0
  int bid = blockIdx.x;
  int cpx = gridDim.x >> 3;
  int swz = (bid & 7) * cpx + (bid >> 3);
  int tm = swz >> 4;                 // 32 M-tiles
  int tn = swz & 15;                 // 16 N-tiles
  int m0 = tm * BM, n0 = tn * BN;

  int tid = threadIdx.x;
  int lane = tid & 63;
  int wid = tid >> 6;                // 8 waves
  int wr = wid >> 2, wc = wid & 3;   // 2 x 4

  // hoisted lane addressing (R4, validated)
  const int xorv = (lane & 7) << 4;
  const int hi4 = (lane >> 4) << 4;
  const int wrbase = wr * 64 + (lane & 15);
  const int wcbase = wc * 32 + (lane & 15);
  const int a_off0 = (wrbase << 7) + (hi4 ^ xorv);
  const int a_off1 = (wrbase << 7) + ((64 | hi4) ^ xorv);
  const int b_off0 = 65536 + (wcbase << 7) + (hi4 ^ xorv);
  const int b_off1 = 65536 + (wcbase << 7) + ((64 | hi4) ^ xorv);
  const int wslot = (tid >> 6) << 10;
  const int s_lr0 = tid >> 3, s_lr1 = 64 + (tid >> 3);
  const int s_off0 = s_lr0 * K_DIM + (((tid & 7) ^ (s_lr0 & 7)) << 3);
  const int s_off1 = s_lr1 * K_DIM + (((tid & 7) ^ (s_lr1 & 7)) << 3);

  // ping-pong operand sets (static names only — rule #20)
  short8 a0_[4][2], a1_[4][2], b0_[2][2], b1_[2][2];
  f32x4 acc[2][2][4][2];
#pragma unroll
  for (int i = 0; i < 2; ++i)
#pragma unroll
    for (int j = 0; j < 2; ++j)
#pragma unroll
      for (int mf = 0; mf < 4; ++mf)
#pragma unroll
        for (int nf = 0; nf < 2; ++nf) acc[i][j][mf][nf] = (f32x4){0.f, 0.f, 0.f, 0.f};

  // prologue: buf0 <- kt0 (B00,A00,B01,A01), buf1 A-q0 <- kt1.
  // vmcnt(2): buf0's 8 loads landed; barrier; then load p1's operand sets.
  STG_B(0, 0, 0); STG_A(0, 0, 0); STG_B(0, 1, 0); STG_A(0, 1, 0);
  STG_A(1, 0, 1);
  VMCNT2;
  __builtin_amdgcn_s_barrier();
  LA_ALL(a0_, 0, 0); LB_ALL(b0_, 0, 0);

  for (int t = 0; t < 31; ++t) {
    const int kt1 = 2 * t + 1;     // buf0 = kt1-1, buf1 = kt1
    REGION(0,0, a0_,b0_, LB_ALL(b1_,0,1),  STG_B(1,0,kt1),   NOOP,            VMCNT2);
    REGION(0,1, a0_,b1_, LA_ALL(a1_,0,1),  STG_B(1,1,kt1),   NOOP,            VMCNT2);
    REGION(1,1, a1_,b1_, LA_K(a0_,1,0,0),  STG_A(1,1,kt1),   NOOP,            VMCNT2);
    REGION(1,0, a1_,b0_, LA_K(a0_,1,0,1),  STG_B(0,0,kt1+1), LB_ALL(b0_,1,0), VMCNT2);
    REGION(0,0, a0_,b0_, LB_ALL(b1_,1,1),  STG_A(0,0,kt1+1), NOOP,            VMCNT2);
    REGION(0,1, a0_,b1_, LA_ALL(a1_,1,1),  STG_B(0,1,kt1+1), NOOP,            VMCNT2);
    REGION(1,1, a1_,b1_, NOOP,             STG_A(0,1,kt1+1), NOOP,            VMCNT2);
    REGION(1,0, a1_,b0_, LA_ALL(a0_,0,0),  STG_A(1,0,kt1+2), LB_ALL(b0_,0,0), VMCNT2);
  }
  // peel: buf0 = kt62, buf1 = kt63; no OOB stages; vmcnt0 at p5 drains the
  // A(1,1,63) pair (staged p3) before p6's read.
  REGION(0,0, a0_,b0_, LB_ALL(b1_,0,1),  STG_B(1,0,63), NOOP,            VMCNT2);
  REGION(0,1, a0_,b1_, LA_ALL(a1_,0,1),  STG_B(1,1,63), NOOP,            VMCNT2);
  REGION(1,1, a1_,b1_, LA_K(a0_,1,0,0),  STG_A(1,1,63), NOOP,            VMCNT2);
  REGION(1,0, a1_,b0_, LA_K(a0_,1,0,1),  NOOP,          LB_ALL(b0_,1,0), VMCNT2);
  REGION(0,0, a0_,b0_, LB_ALL(b1_,1,1),  NOOP,          NOOP,            VMCNT0);
  REGION(0,1, a0_,b1_, LA_ALL(a1_,1,1),  NOOP,          NOOP,            NOOP);
  REGION(1,1, a1_,b1_, NOOP,             NOOP,          NOOP,            NOOP);
  REGION(1,0, a1_,b0_, NOOP,             NOOP,          NOOP,            NOOP);

  // epilogue: C/D layout col=lane&15, row=(lane>>4)*4+j
#pragma unroll
  for (int qn = 0; qn < 2; ++qn)
#pragma unroll
    for (int nf = 0; nf < 2; ++nf) {
      int gcol = n0 + qn * 128 + wc * 32 + nf * 16 + (lane & 15);
      float bv = bias[gcol];
#pragma unroll
      for (int qm = 0; qm < 2; ++qm)
#pragma unroll
        for (int mf = 0; mf < 4; ++mf) {
          int grow = m0 + qm * 128 + wr * 64 + mf * 16 + ((lane >> 4) << 2);
          f32x4 v = acc[qm][qn][mf][nf];
#pragma unroll
          for (int j = 0; j < 4; ++j)
            C[(size_t)(grow + j) * N_DIM + gcol] = v[j] + bv;
        }
    }
}

extern "C" void kernel_launch(void* const* d_in, const int* in_sizes, int n_in,
                              void* d_out, int out_size, void* d_ws, size_t ws_size,
                              hipStream_t stream) {
  const float* x       = (const float*)d_in[0];
  const int*   qweight = (const int*)d_in[1];
  const float* scale   = (const float*)d_in[2];
  const float* zero    = (const float*)d_in[3];
  const float* bias    = (const float*)d_in[4];
  float* out = (float*)d_out;

  unsigned short* Xb = (unsigned short*)d_ws;                    // 64 MB
  unsigned short* Wb = Xb + (size_t)M_DIM * K_DIM;               // 32 MB

  cast_x_kernel<<<(M_DIM * K_DIM / 8) / 256, 256, 0, stream>>>(x, Xb);
  dequant_kernel<<<(N_DIM * 128) / 256, 256, 0, stream>>>(qweight, scale, zero, Wb);
  gemm_kernel<<<(M_DIM / BM) * (N_DIM / BN), 512, 0, stream>>>(Xb, Wb, bias, out);
}

// Round 8
// 263.095 us; speedup vs baseline: 1.0450x; 1.0450x over previous
//
#include <hip/hip_runtime.h>
#include <hip/hip_bf16.h>
#include <stdint.h>

typedef __attribute__((ext_vector_type(8))) short short8;
typedef __attribute__((ext_vector_type(4))) float f32x4;

#define M_DIM 8192
#define N_DIM 4096
#define K_DIM 4096
#define BM 256
#define BN 256
#define BK 64

static __device__ __forceinline__ unsigned short f32_to_bf16(float f) {
  union { float f; unsigned int u; } v; v.f = f;
  unsigned int u = v.u;
  u += 0x7fffu + ((u >> 16) & 1u);   // round-to-nearest-even
  return (unsigned short)(u >> 16);
}

// ---------------- cast x (f32 -> bf16), 8 elems/thread ----------------
__global__ void cast_x_kernel(const float* __restrict__ x,
                              unsigned short* __restrict__ xb) {
  size_t i = ((size_t)blockIdx.x * blockDim.x + threadIdx.x) * 8;
  if (i >= (size_t)M_DIM * K_DIM) return;
  float4 v0 = *reinterpret_cast<const float4*>(x + i);
  float4 v1 = *reinterpret_cast<const float4*>(x + i + 4);
  short8 o;
  o[0] = (short)f32_to_bf16(v0.x);
  o[1] = (short)f32_to_bf16(v0.y);
  o[2] = (short)f32_to_bf16(v0.z);
  o[3] = (short)f32_to_bf16(v0.w);
  o[4] = (short)f32_to_bf16(v1.x);
  o[5] = (short)f32_to_bf16(v1.y);
  o[6] = (short)f32_to_bf16(v1.z);
  o[7] = (short)f32_to_bf16(v1.w);
  *reinterpret_cast<short8*>(xb + i) = o;
}

// ---------------- dequant: bit-planes -> bf16 W[N][K] (validated) ----------
__global__ void dequant_kernel(const int* __restrict__ qw,
                               const float* __restrict__ scale,
                               const float* __restrict__ zero,
                               unsigned short* __restrict__ W) {
  int idx = blockIdx.x * blockDim.x + threadIdx.x;   // n*128 + c
  if (idx >= N_DIM * 128) return;
  int n = idx >> 7;
  int c = idx & 127;
  unsigned int w[8];
#pragma unroll
  for (int k = 0; k < 8; ++k)
    w[k] = (unsigned int)qw[(size_t)k * (N_DIM * 128) + idx];
  int wp = c >> 5, t = c & 31;
#pragma unroll
  for (int s = 0; s < 4; ++s) {
    int r = s ^ 3;
    unsigned int by[8];
#pragma unroll
    for (int k = 0; k < 8; ++k) by[k] = (w[k] >> (8 * r)) & 0xffu;
    int ibase = wp * 1024 + s * 256 + t * 8;
    int g = ibase >> 7;
    float sc = scale[n * 32 + g];
    float zp = zero[n * 32 + g] * 16.0f;
    short8 o;
#pragma unroll
    for (int u = 0; u < 8; ++u) {
      unsigned int q = 0;
#pragma unroll
      for (int k = 0; k < 8; ++k)
        q |= ((by[k] >> (7 - u)) & 1u) << (7 - k);
      o[u] = (short)f32_to_bf16(sc * ((float)q - zp));
    }
    *reinterpret_cast<short8*>(&W[(size_t)n * K_DIM + ibase]) = o;
  }
}

// ---- 256x256 8-region bf16 GEMM (R6 skeleton + compiler-counted lgkm) ----
// C[M][N] = A[M][K] * B[N][K]^T + bias. 8 waves (2Mx4N), wave out 128x64.
// Region p: bar; vmcnt(2); SB0; prio1; stage; kk0-MFMA(8); rd(p+1,kk0); SB0;
//           kk1-MFMA(8); rd(p+1,kk1); SB0; prio0.
// R8 change vs R6 (213us, verified): NO explicit lgkmcnt(0) at entry — the
// ds_reads are compiler-visible loads, so hipcc's waitcnt pass emits PRECISE
// counted lgkm waits before each consuming MFMA octet; octet1 starts while
// RD1's reads (late-issued in p-1) still drain under it. Cross-wave
// visibility unchanged (stage/vmcnt/barrier ledger identical to R6):
// pair staged at s -> all-waves drain at s+1..s+2 entry -> read at >= s+3;
// prologue drains buf0 (vmcnt(2)) + barrier BEFORE any cross-slot ds_read;
// peel pulls the A(1,1,63) drain to p5 (vmcnt(0)).

#define VMCNT2 asm volatile("s_waitcnt vmcnt(2)" ::: "memory")
#define VMCNT0 asm volatile("s_waitcnt vmcnt(0)" ::: "memory")
#define NOOP ((void)0)

#define STG(G, GROWB, KT, LDSC) do {                                           \
  const unsigned short* sb_ = (G) + ((size_t)(GROWB) * K_DIM + (KT) * 64);     \
  __builtin_amdgcn_global_load_lds(                                            \
      (const __attribute__((address_space(1))) void*)(sb_ + s_off0),           \
      (__attribute__((address_space(3))) void*)(smem + (LDSC) + wslot),        \
      16, 0, 0);                                                               \
  __builtin_amdgcn_global_load_lds(                                            \
      (const __attribute__((address_space(1))) void*)(sb_ + s_off1),           \
      (__attribute__((address_space(3))) void*)(smem + (LDSC) + 8192 + wslot), \
      16, 0, 0);                                                               \
} while (0)
#define STG_A(BUF, H, KT) STG(Ag, m0 + (H)*128, (KT), ((BUF)*2 + (H)) * 16384)
#define STG_B(BUF, H, KT) STG(Bg, n0 + (H)*128, (KT), 65536 + ((BUF)*2 + (H)) * 16384)

// reads for ONE k-slot (KK literal): 4 A-frags or 2 B-frags
#define LA(BUF, QM, KK) do {                                                   \
  _Pragma("unroll") for (int mf_ = 0; mf_ < 4; ++mf_)                          \
    a_[mf_][KK] = *(const short8*)(smem + ((KK) ? a_off1 : a_off0) +           \
        (((BUF)*2 + (QM)) * 16384 + mf_ * 2048));                              \
} while (0)
#define LB(BUF, QN, KK) do {                                                   \
  _Pragma("unroll") for (int nf_ = 0; nf_ < 2; ++nf_)                          \
    b_[nf_][KK] = *(const short8*)(smem + ((KK) ? b_off1 : b_off0) +           \
        (((BUF)*2 + (QN)) * 16384 + nf_ * 2048));                              \
} while (0)

#define MFMA_KK(QM, QN, KK)                                                    \
  _Pragma("unroll") for (int mf_ = 0; mf_ < 4; ++mf_)                          \
    _Pragma("unroll") for (int nf_ = 0; nf_ < 2; ++nf_)                        \
      acc[QM][QN][mf_][nf_] = __builtin_amdgcn_mfma_f32_16x16x32_bf16(         \
          a_[mf_][KK], b_[nf_][KK], acc[QM][QN][mf_][nf_], 0, 0, 0)

// one region; RD0/RD1 load operands for the NEXT region's MFMAs.
// WAR deps (RD0 overwrites [*][0] read by octet1) keep intra-region order.
#define REGION(QM, QN, RD0, RD1, STAGE, WAITV) do {                            \
  __builtin_amdgcn_s_barrier();                                                \
  WAITV;                                                                       \
  __builtin_amdgcn_sched_barrier(0);                                           \
  __builtin_amdgcn_s_setprio(1);                                               \
  STAGE;                                                                       \
  MFMA_KK(QM, QN, 0);                                                          \
  RD0;                                                                         \
  __builtin_amdgcn_sched_barrier(0);                                           \
  MFMA_KK(QM, QN, 1);                                                          \
  RD1;                                                                         \
  __builtin_amdgcn_sched_barrier(0);                                           \
  __builtin_amdgcn_s_setprio(0);                                               \
} while (0)

__global__ __launch_bounds__(512, 2) void gemm_kernel(
    const unsigned short* __restrict__ Ag,   // Xb [M][K] bf16
    const unsigned short* __restrict__ Bg,   // Wb [N][K] bf16
    const float* __restrict__ bias,
    float* __restrict__ C) {
  __shared__ __align__(16) char smem[131072];   // A: [0,64K), B: [64K,128K)

  // XCD-aware bijective swizzle: 512 blocks % 8 == 0
  int bid = blockIdx.x;
  int cpx = gridDim.x >> 3;
  int swz = (bid & 7) * cpx + (bid >> 3);
  int tm = swz >> 4;                 // 32 M-tiles
  int tn = swz & 15;                 // 16 N-tiles
  int m0 = tm * BM, n0 = tn * BN;

  int tid = threadIdx.x;
  int lane = tid & 63;
  int wid = tid >> 6;                // 8 waves
  int wr = wid >> 2, wc = wid & 3;   // 2 x 4

  // hoisted lane addressing (R4, validated)
  const int xorv = (lane & 7) << 4;
  const int hi4 = (lane >> 4) << 4;
  const int wrbase = wr * 64 + (lane & 15);
  const int wcbase = wc * 32 + (lane & 15);
  const int a_off0 = (wrbase << 7) + (hi4 ^ xorv);
  const int a_off1 = (wrbase << 7) + ((64 | hi4) ^ xorv);
  const int b_off0 = 65536 + (wcbase << 7) + (hi4 ^ xorv);
  const int b_off1 = 65536 + (wcbase << 7) + ((64 | hi4) ^ xorv);
  const int wslot = (tid >> 6) << 10;
  const int s_lr0 = tid >> 3, s_lr1 = 64 + (tid >> 3);
  const int s_off0 = s_lr0 * K_DIM + (((tid & 7) ^ (s_lr0 & 7)) << 3);
  const int s_off1 = s_lr1 * K_DIM + (((tid & 7) ^ (s_lr1 & 7)) << 3);

  short8 a_[4][2], b_[2][2];
  f32x4 acc[2][2][4][2];
#pragma unroll
  for (int i = 0; i < 2; ++i)
#pragma unroll
    for (int j = 0; j < 2; ++j)
#pragma unroll
      for (int mf = 0; mf < 4; ++mf)
#pragma unroll
        for (int nf = 0; nf < 2; ++nf) acc[i][j][mf][nf] = (f32x4){0.f, 0.f, 0.f, 0.f};

  // prologue: buf0 <- kt0 (B00,A00,B01,A01), buf1 A10 <- kt1.
  // vmcnt(2): ALL buf0 loads landed; barrier; then cross-slot ds_reads.
  STG_B(0, 0, 0); STG_A(0, 0, 0); STG_B(0, 1, 0); STG_A(0, 1, 0);
  STG_A(1, 0, 1);
  VMCNT2;
  __builtin_amdgcn_s_barrier();
  LA(0, 0, 0); LB(0, 0, 0); LA(0, 0, 1); LB(0, 0, 1);  // reads for region 1

  for (int t = 0; t < 31; ++t) {
    const int kt1 = 2 * t + 1;     // buf0 = kt1-1, buf1 = kt1
    REGION(0, 0, LB(0,1,0),            LB(0,1,1),            STG_B(1,0,kt1),   VMCNT2);
    REGION(0, 1, LA(0,1,0),            LA(0,1,1),            STG_B(1,1,kt1),   VMCNT2);
    REGION(1, 1, LB(0,0,0),            LB(0,0,1),            STG_A(1,1,kt1),   VMCNT2);
    REGION(1, 0, LA(1,0,0); LB(1,0,0), LA(1,0,1); LB(1,0,1), STG_B(0,0,kt1+1), VMCNT2);
    REGION(0, 0, LB(1,1,0),            LB(1,1,1),            STG_A(0,0,kt1+1), VMCNT2);
    REGION(0, 1, LA(1,1,0),            LA(1,1,1),            STG_B(0,1,kt1+1), VMCNT2);
    REGION(1, 1, LB(1,0,0),            LB(1,0,1),            STG_A(0,1,kt1+1), VMCNT2);
    REGION(1, 0, LA(0,0,0); LB(0,0,0), LA(0,0,1); LB(0,0,1), STG_A(1,0,kt1+2), VMCNT2);
  }
  // peeled final iteration: buf0 = 62, buf1 = 63; no OOB stages.
  // Drain of A11(63) pulled to p5 (vmcnt(0)) so p6's read is barrier-separated.
  REGION(0, 0, LB(0,1,0),            LB(0,1,1),            STG_B(1,0,63), VMCNT2);
  REGION(0, 1, LA(0,1,0),            LA(0,1,1),            STG_B(1,1,63), VMCNT2);
  REGION(1, 1, LB(0,0,0),            LB(0,0,1),            STG_A(1,1,63), VMCNT2);
  REGION(1, 0, LA(1,0,0); LB(1,0,0), LA(1,0,1); LB(1,0,1), NOOP,          VMCNT2);
  REGION(0, 0, LB(1,1,0),            LB(1,1,1),            NOOP,          VMCNT0);
  REGION(0, 1, LA(1,1,0),            LA(1,1,1),            NOOP,          NOOP);
  REGION(1, 1, LB(1,0,0),            LB(1,0,1),            NOOP,          NOOP);
  REGION(1, 0, NOOP,                 NOOP,                 NOOP,          NOOP);

  // epilogue: C/D layout col=lane&15, row=(lane>>4)*4+j
#pragma unroll
  for (int qn = 0; qn < 2; ++qn)
#pragma unroll
    for (int nf = 0; nf < 2; ++nf) {
      int gcol = n0 + qn * 128 + wc * 32 + nf * 16 + (lane & 15);
      float bv = bias[gcol];
#pragma unroll
      for (int qm = 0; qm < 2; ++qm)
#pragma unroll
        for (int mf = 0; mf < 4; ++mf) {
          int grow = m0 + qm * 128 + wr * 64 + mf * 16 + ((lane >> 4) << 2);
          f32x4 v = acc[qm][qn][mf][nf];
#pragma unroll
          for (int j = 0; j < 4; ++j)
            C[(size_t)(grow + j) * N_DIM + gcol] = v[j] + bv;
        }
    }
}

extern "C" void kernel_launch(void* const* d_in, const int* in_sizes, int n_in,
                              void* d_out, int out_size, void* d_ws, size_t ws_size,
                              hipStream_t stream) {
  const float* x       = (const float*)d_in[0];
  const int*   qweight = (const int*)d_in[1];
  const float* scale   = (const float*)d_in[2];
  const float* zero    = (const float*)d_in[3];
  const float* bias    = (const float*)d_in[4];
  float* out = (float*)d_out;

  unsigned short* Xb = (unsigned short*)d_ws;                    // 64 MB
  unsigned short* Wb = Xb + (size_t)M_DIM * K_DIM;               // 32 MB

  cast_x_kernel<<<(M_DIM * K_DIM / 8) / 256, 256, 0, stream>>>(x, Xb);
  dequant_kernel<<<(N_DIM * 128) / 256, 256, 0, stream>>>(qweight, scale, zero, Wb);
  gemm_kernel<<<(M_DIM / BM) * (N_DIM / BN), 512, 0, stream>>>(Xb, Wb, bias, out);
}